// Round 5
// baseline (354.395 us; speedup 1.0000x reference)
//
#include <hip/hip_runtime.h>
#include <math.h>

// ---------------------------------------------------------------------------
// MinGRU, 2 layers. B=8, S=4096, D=H=512.
// Round 5: r4 + (1) two-pass epilogue aliasing the staging LDS (19.5 KB total
// -> ~6 blocks/CU), (2) XCD-swizzled block decode (A-tile fetched once per
// L2: 8 bn-blocks of one bm land time-adjacent on one XCD), (3) Lc=32
// (Nc=128) for 2x pass3 parallelism. 7 dispatches.
// ---------------------------------------------------------------------------

typedef unsigned short u16;
typedef __attribute__((ext_vector_type(8))) short short8;   // 8 bf16 = 4 VGPR
typedef __attribute__((ext_vector_type(4))) float f32x4;

__device__ __forceinline__ u16 f2bf(float f) {
    unsigned int u = __float_as_uint(f);
    return (u16)((u + 0x7fffu + ((u >> 16) & 1u)) >> 16);   // RNE
}
__device__ __forceinline__ float bf2f(u16 u) {
    return __uint_as_float(((unsigned int)u) << 16);
}
__device__ __forceinline__ void async16(const void* g, void* l) {
    __builtin_amdgcn_global_load_lds(
        (const __attribute__((address_space(1))) unsigned int*)g,
        (__attribute__((address_space(3))) unsigned int*)l, 16, 0, 0);
}

__device__ __forceinline__ void coeff_val(float gate, float hid, float& c, float& v)
{
    float eg  = __expf(-fabsf(gate));
    float inv = 1.0f / (1.0f + eg);
    float sp  = inv;                       // sigmoid(|gate|)
    float sn  = eg * inv;                  // sigmoid(-|gate|)
    float z   = (gate >= 0.f) ? sp : sn;   // sigmoid(gate)
    c         = (gate >= 0.f) ? sn : sp;   // sigmoid(-gate)
    float eh  = __expf(-fabsf(hid));
    float gneg = eh / (1.0f + eh);
    float g   = (hid >= 0.f) ? (hid + 0.5f) : gneg;
    v = z * g;
}

// ---------------------------------------------------------------------------
// Fused cast: x, w0, w1 in one flat grid.
// ---------------------------------------------------------------------------
__global__ __launch_bounds__(256) void cast3(
    const float* __restrict__ x,  u16* __restrict__ xb,  int nx4,
    const float* __restrict__ w0, u16* __restrict__ w0b,
    const float* __restrict__ w1, u16* __restrict__ w1b, int nw4)
{
    int i = blockIdx.x * 256 + threadIdx.x;
    const float* src; u16* dst; int idx;
    if (i < nx4)                { src = x;  dst = xb;  idx = i; }
    else if (i < nx4 + nw4)     { src = w0; dst = w0b; idx = i - nx4; }
    else if (i < nx4 + 2 * nw4) { src = w1; dst = w1b; idx = i - nx4 - nw4; }
    else return;
    float4 v = ((const float4*)src)[idx];
    ushort4 o = make_ushort4(f2bf(v.x), f2bf(v.y), f2bf(v.z), f2bf(v.w));
    ((ushort4*)dst)[idx] = o;
}

// ---------------------------------------------------------------------------
// gemm_fused: per 128-row x 64-channel block: GEMM (bf16 MFMA) + bias +
// coalesced bf16 gh store via LDS + in-LDS 32-row chunk summaries.
// Flat grid 2048, XCD-swizzled: xcd=id&7, bn=(id>>3)&7, bm=(id>>6)*8+xcd.
// W row permutation: tile row r<64 -> gate row bn*64+r; r>=64 -> hidden row
// 512+bn*64+(r-64). Lc=32, Nc=128 hardcoded.
// ---------------------------------------------------------------------------
#define TSTR 136   // epilogue C-half-tile row stride in u16 (272 B, 16B-aligned)

__global__ __launch_bounds__(256) void gemm_fused(
    const u16* __restrict__ A, const u16* __restrict__ W,
    const float* __restrict__ bias, u16* __restrict__ gh,
    float* __restrict__ cA, float* __restrict__ cV, int K)
{
    // buf aliases: K-loop staging (Asm = buf[0..4095], Wsm = buf[4096..8191])
    // and the 64-row epilogue tile (64*TSTR = 8704 u16 = 17408 B).
    __shared__ __align__(16) u16 buf[64 * TSTR];
    __shared__ float2 csum[2][2][64];               // [chunk32][rowhalf][ch]

    u16* Asm = buf;
    u16* Wsm = buf + 4096;

    const int tid  = threadIdx.x;
    const int id   = blockIdx.x;
    const int xcd  = id & 7;
    const int bn   = (id >> 3) & 7;          // channel block: [bn*64, bn*64+64)
    const int bm   = (id >> 6) * 8 + xcd;    // row block, XCD-affine
    const int lane = tid & 63;
    const int wave = tid >> 6;
    const int wm   = (wave >> 1) * 64;
    const int wn   = (wave & 1) * 64;
    const int fm   = lane & 15;
    const int kb   = lane >> 4;

    // staging granules (swizzled quarters, read-side involution)
    const int g0 = tid, g1 = tid + 256;
    const int r0 = g0 >> 2, q0 = (g0 & 3) ^ ((g0 >> 3) & 3);   // r0 in [0,64)
    const int r1 = g1 >> 2, q1 = (g1 & 3) ^ ((g1 >> 3) & 3);   // r1 in [64,128)
    const int wr0 = bn * 64 + (r0 & 63) + ((r0 >> 6) << 9);    // gate rows
    const int wr1 = bn * 64 + (r1 & 63) + ((r1 >> 6) << 9);    // hidden rows
    const u16* Ap0 = A + (size_t)(bm * 128 + r0) * K + q0 * 8;
    const u16* Ap1 = A + (size_t)(bm * 128 + r1) * K + q1 * 8;
    const u16* Wp0 = W + (size_t)wr0 * K + q0 * 8;
    const u16* Wp1 = W + (size_t)wr1 * K + q1 * 8;
    char* lA0 = (char*)Asm + g0 * 16;
    char* lA1 = (char*)Asm + g1 * 16;
    char* lW0 = (char*)Wsm + g0 * 16;
    char* lW1 = (char*)Wsm + g1 * 16;

    int offA[4], offB[4];
    #pragma unroll
    for (int i = 0; i < 4; ++i) {
        int rowA = wm + i * 16 + fm;
        offA[i] = rowA * 64 + ((kb ^ ((rowA >> 1) & 3)) * 16);
        int rowB = wn + i * 16 + fm;
        offB[i] = rowB * 64 + ((kb ^ ((rowB >> 1) & 3)) * 16);
    }

    f32x4 acc[4][4];
    #pragma unroll
    for (int i = 0; i < 4; ++i)
        #pragma unroll
        for (int j = 0; j < 4; ++j)
            acc[i][j] = (f32x4){0.f, 0.f, 0.f, 0.f};

    const char* AsB = (const char*)Asm;
    const char* WsB = (const char*)Wsm;

    for (int kt = 0; kt < K; kt += 32) {
        async16(Ap0, lA0);
        async16(Ap1, lA1);
        async16(Wp0, lW0);
        async16(Wp1, lW1);
        __syncthreads();
        short8 a[4], b[4];
        #pragma unroll
        for (int i = 0; i < 4; ++i) a[i] = *(const short8*)(AsB + offA[i]);
        #pragma unroll
        for (int j = 0; j < 4; ++j) b[j] = *(const short8*)(WsB + offB[j]);
        #pragma unroll
        for (int i = 0; i < 4; ++i)
            #pragma unroll
            for (int j = 0; j < 4; ++j)
                acc[i][j] = __builtin_amdgcn_mfma_f32_16x16x32_bf16(
                    a[i], b[j], acc[i][j], 0, 0, 0);
        __syncthreads();                 // LDS reads done -> buf reusable
        Ap0 += 32; Ap1 += 32; Wp0 += 32; Wp1 += 32;
    }

    // ---- epilogue: two 64-row passes through the (aliased) 17.4 KB buf ----
    float bv[4];
    #pragma unroll
    for (int j = 0; j < 4; ++j) {
        int c = wn + j * 16 + fm;
        bv[j] = bias[bn * 64 + (c & 63) + ((c >> 6) << 9)];
    }

    const int ch  = tid & 63;          // channel within block
    const int ckl = (tid >> 6) & 1;    // 32-row chunk within 64-row half
    const int hh  = tid >> 7;          // 16-row half within chunk
    const int bb  = bm >> 5;           // batch (32 row-blocks per batch)

    #pragma unroll
    for (int p = 0; p < 2; ++p) {      // p: tile rows [p*64, p*64+64)
        if ((wave >> 1) == p) {        // waves owning these rows
            #pragma unroll
            for (int i = 0; i < 4; ++i)
                #pragma unroll
                for (int j = 0; j < 4; ++j) {
                    const int col = wn + j * 16 + fm;
                    f32x4 v = acc[i][j];
                    #pragma unroll
                    for (int r = 0; r < 4; ++r)
                        buf[(i * 16 + kb * 4 + r) * TSTR + col] = f2bf(v[r] + bv[j]);
                }
        }
        __syncthreads();

        // coalesced gh store: tile col c<64 -> gate, c>=64 -> hidden
        #pragma unroll
        for (int it = 0; it < 4; ++it) {
            const int h   = it & 1;
            const int row = (it >> 1) * 32 + (tid >> 3);
            const int sc  = (tid & 7) * 8;
            short8 vv = *(const short8*)&buf[row * TSTR + h * 64 + sc];
            *(short8*)&gh[(size_t)(bm * 128 + p * 64 + row) * 1024 + h * 512 + bn * 64 + sc] = vv;
        }

        // 16-row scan partials
        float Aa = 1.f, Vv = 0.f;
        const int rbase = ckl * 32 + hh * 16;
        #pragma unroll 4
        for (int s = 0; s < 16; ++s) {
            const int row = rbase + s;
            float gate = bf2f(buf[row * TSTR + ch]);
            float hid  = bf2f(buf[row * TSTR + 64 + ch]);
            float c, v; coeff_val(gate, hid, c, v);
            Aa *= c;
            Vv = fmaf(c, Vv, v);
        }
        csum[ckl][hh][ch] = make_float2(Aa, Vv);
        __syncthreads();               // buf reads + csum writes done

        if (hh == 0) {                 // combine halves -> 32-row chunk summary
            float2 s0 = csum[ckl][0][ch];     // rows [0,16) of chunk
            float2 s1 = csum[ckl][1][ch];     // rows [16,32)
            float Ac = s0.x * s1.x;
            float Vc = fmaf(s1.x, s0.y, s1.y);
            const int ckg = (bm & 31) * 4 + p * 2 + ckl;   // chunk in [0,128)
            const size_t idx = ((size_t)(bb * 128 + ckg)) * 512 + bn * 64 + ch;
            cA[idx] = Ac;
            cV[idx] = Vc;
        }
        // next p: waves (wave>>1)==1 overwrite buf right away — safe, the
        // barrier above covered all buf reads; combine touches only csum/cA/cV.
    }
}

// ---------------------------------------------------------------------------
// pass2: sequential combine across Nc chunks per batch. 2 channels/thread.
// ---------------------------------------------------------------------------
__global__ __launch_bounds__(256) void scan_pass2(
    const float* __restrict__ cA, const float* __restrict__ cV,
    float* __restrict__ carry, int Nc)
{
    const int tid = threadIdx.x;
    const int b = blockIdx.x;
    float s0 = 0.5f, s1 = 0.5f;   // h0
    #pragma unroll 8
    for (int ck = 0; ck < Nc; ++ck) {
        const size_t idx = (size_t)(b * Nc + ck) * 512 + 2 * tid;
        *(float2*)(carry + idx) = make_float2(s0, s1);
        float2 a = *(const float2*)(cA + idx);
        float2 v = *(const float2*)(cV + idx);
        s0 = fmaf(a.x, s0, v.x);
        s1 = fmaf(a.y, s1, v.y);
    }
}

// ---------------------------------------------------------------------------
// pass3: replay each chunk from its carry, write all h_t (+ last-step h).
// ---------------------------------------------------------------------------
template <bool OUT_BF16>
__global__ __launch_bounds__(256) void scan_pass3(
    const u16* __restrict__ gh, const float* __restrict__ carry,
    void* __restrict__ outv, float* __restrict__ nh,
    int S, int Lc, int Nc)
{
    const int tid = threadIdx.x;
    const int b  = blockIdx.x / Nc;
    const int ck = blockIdx.x % Nc;
    const u16* base = gh + (size_t)(b * S + ck * Lc) * 1024 + 2 * tid;
    const size_t cidx = (size_t)(b * Nc + ck) * 512 + 2 * tid;
    float2 st = *(const float2*)(carry + cidx);
    float h0 = st.x, h1 = st.y;
    const size_t obase = (size_t)(b * S + ck * Lc) * 512 + 2 * tid;
    #pragma unroll 4
    for (int s = 0; s < Lc; ++s) {
        ushort2 g2 = *(const ushort2*)(base + (size_t)s * 1024);
        ushort2 h2 = *(const ushort2*)(base + (size_t)s * 1024 + 512);
        float c0, v0, c1, v1;
        coeff_val(bf2f(g2.x), bf2f(h2.x), c0, v0);
        coeff_val(bf2f(g2.y), bf2f(h2.y), c1, v1);
        h0 = fmaf(c0, h0, v0);
        h1 = fmaf(c1, h1, v1);
        if (OUT_BF16) {
            ushort2 o = make_ushort2(f2bf(h0), f2bf(h1));
            *(ushort2*)((u16*)outv + obase + (size_t)s * 512) = o;
        } else {
            *(float2*)((float*)outv + obase + (size_t)s * 512) = make_float2(h0, h1);
        }
    }
    if (ck == Nc - 1)
        *(float2*)(nh + (size_t)b * 512 + 2 * tid) = make_float2(h0, h1);
}

// ---------------------------------------------------------------------------
extern "C" void kernel_launch(void* const* d_in, const int* in_sizes, int n_in,
                              void* d_out, int out_size, void* d_ws, size_t ws_size,
                              hipStream_t stream)
{
    const float* x  = (const float*)d_in[0];
    const float* w0 = (const float*)d_in[1];
    const float* b0 = (const float*)d_in[2];
    const float* w1 = (const float*)d_in[3];
    const float* b1 = (const float*)d_in[4];
    float* out = (float*)d_out;

    const int B = 8, S = 4096, K = 512;
    const int M = B * S;             // 32768
    const int Lc = 32, Nc = S / Lc;  // 128 chunks of 32

    // workspace (bf16 elems): gh M*1024, xb M*512, h0b M*512, w0b/w1b 1024*512
    u16* gh  = (u16*)d_ws;
    u16* xb  = gh  + (size_t)M * 1024;
    u16* h0b = xb  + (size_t)M * 512;
    u16* w0b = h0b + (size_t)M * 512;
    u16* w1b = w0b + (size_t)1024 * 512;
    float* cA    = (float*)(w1b + (size_t)1024 * 512);
    float* cV    = cA + (size_t)B * Nc * 512;
    float* carry = cV + (size_t)B * Nc * 512;

    float* nh0 = out + (size_t)M * 512;
    float* nh1 = nh0 + (size_t)B * 512;

    dim3 blk(256);
    dim3 ggrid(8 * (M / 128));       // 2048 flat, XCD-swizzled in-kernel
    dim3 sgrid(B * Nc);              // 1024

    const int nx4 = M * K / 4;           // 4,194,304
    const int nw4 = 1024 * K / 4;        // 131,072
    cast3<<<dim3((nx4 + 2 * nw4 + 255) / 256), blk, 0, stream>>>(
        x, xb, nx4, w0, w0b, w1, w1b, nw4);

    // ---- layer 0 ----
    gemm_fused<<<ggrid, blk, 0, stream>>>(xb, w0b, b0, gh, cA, cV, K);
    scan_pass2<<<dim3(B), blk, 0, stream>>>(cA, cV, carry, Nc);
    scan_pass3<true><<<sgrid, blk, 0, stream>>>(gh, carry, h0b, nh0, S, Lc, Nc);

    // ---- layer 1 ----
    gemm_fused<<<ggrid, blk, 0, stream>>>(h0b, w1b, b1, gh, cA, cV, K);
    scan_pass2<<<dim3(B), blk, 0, stream>>>(cA, cV, carry, Nc);
    scan_pass3<false><<<sgrid, blk, 0, stream>>>(gh, carry, out, nh1, S, Lc, Nc);
}